// Round 2
// baseline (227.456 us; speedup 1.0000x reference)
//
#include <hip/hip_runtime.h>
#include <math.h>

// DivEncoder: x[N,H] -> per-group (D=512 groups, V=16) conv to U=64, ELU,
// conv U->1, row-wise L2 normalize. All fp32 in/out.
#define D_ 512
#define H_ 8192
#define U_ 64
#define V_ 16
#define N_ 4096
#define DUV (D_ * U_ * V_)     // 524288

// k1 geometry: persistent blocks. 64 rows x 8 groups per tile, 256 threads
// (4 waves), each block owns NT=8 consecutive row-tiles of one group-slice.
// Double-buffered x staging: STAGE(t+1) issued before compute(t), one
// __syncthreads per tile (2-phase pipeline, T3-lite). Weights loaded once
// per block and held in registers across all 8 tiles.
#define BR 64
#define BG 8
#define NT 8                   // row-tiles per block
#define CH 8                   // blocks per group-slice (8*8*64 = 4096 rows)
#define YSTR 12                // 8 used + pad -> 16B-aligned f32x4 reads

typedef __bf16 bf16x8 __attribute__((ext_vector_type(8)));
typedef __bf16 bf16x4 __attribute__((ext_vector_type(4)));
typedef float f32x4 __attribute__((ext_vector_type(4)));

typedef const __attribute__((address_space(1))) char* gptr_t;
typedef __attribute__((address_space(3))) char* sptr_t;

// Prep: split W1 fp32 -> hi/lo bf16 (same [d][u][v] layout), once per launch.
__global__ __launch_bounds__(256) void k0_split_w1(const float* __restrict__ W1,
                                                   __bf16* __restrict__ wh) {
    __bf16* wl = wh + DUV;
    const int i4 = (blockIdx.x * 256 + threadIdx.x) * 4;
    f32x4 w = *(const f32x4*)(W1 + i4);
    bf16x4 h, l;
    #pragma unroll
    for (int j = 0; j < 4; ++j) {
        float wf = w[j];
        __bf16 hh = (__bf16)wf;
        h[j] = hh;
        l[j] = (__bf16)(wf - (float)hh);
    }
    *(bf16x4*)(wh + i4) = h;
    *(bf16x4*)(wl + i4) = l;
}

// Split-precision bf16 MFMA (16x16x32): K packs [w_hi | w_lo]:
//   MFMA1 B=[x_hi|x_hi] -> w*x_hi ; MFMA2 B=[x_lo|x_lo] -> w*x_lo
// Layouts (HW-verified): A/B: idx=lane&15, k=(lane>>4)*8+j ;
// C/D: col=lane&15, row=(lane>>4)*4+reg.
// LDS slot (row, s16) holds x[row][s16 ^ ((row&7)<<4)]: source-side swizzle
// keeps the LDS destination linear for global_load_lds; ds_read applies the
// same XOR (rule #21 both-sides). 16 m-lanes/quad -> 8 distinct 16B slots.
template <bool PRESPLIT>
__global__ __launch_bounds__(256, 2) void k1_div_encoder(
        const float* __restrict__ x,
        const float* __restrict__ W1,
        const __bf16* __restrict__ wsplit,
        const float* __restrict__ b1,
        const float* __restrict__ W2,
        const float* __restrict__ b2,
        float* __restrict__ y) {
    __shared__ float xs[2][BR * 128];     // 2 x 32 KB
    __shared__ float yt[2][BR][YSTR];     // 2 x 3 KB

    const int tid  = threadIdx.x;
    const int lane = tid & 63;
    const int wave = __builtin_amdgcn_readfirstlane(tid >> 6);
    const int q    = lane >> 4;
    const int m    = lane & 15;
    const int vbase = (q & 1) * 8;

    const int db    = blockIdx.x >> 3;   // 0..63 group-slice
    const int chunk = blockIdx.x & 7;    // 0..7 row-chunk
    const int d0    = db * BG;

    // ---- load per-block weights once, held in registers for all tiles ----
    bf16x8 Afrag[2][4];
    f32x4  b1f[2][4], w2f[2][4];
    float  b2s[2];
    #pragma unroll
    for (int gi = 0; gi < 2; ++gi) {
        const int d = d0 + wave * 2 + gi;
        if (PRESPLIT) {
            const __bf16* base = wsplit + (size_t)(q >> 1) * DUV;
            #pragma unroll
            for (int c = 0; c < 4; ++c) {
                Afrag[gi][c] = *(const bf16x8*)(base +
                    ((size_t)d * U_ + c * 16 + m) * V_ + vbase);
            }
        } else {
            #pragma unroll
            for (int c = 0; c < 4; ++c) {
                const float* wp = W1 + ((size_t)d * U_ + c * 16 + m) * V_ + vbase;
                f32x4 w0 = *(const f32x4*)wp;
                f32x4 w1v = *(const f32x4*)(wp + 4);
                float wf[8] = {w0.x, w0.y, w0.z, w0.w, w1v.x, w1v.y, w1v.z, w1v.w};
                bf16x8 a;
                #pragma unroll
                for (int i = 0; i < 8; ++i) {
                    __bf16 h = (__bf16)wf[i];
                    __bf16 l = (__bf16)(wf[i] - (float)h);
                    a[i] = (q < 2) ? h : l;   // cndmask, branchless
                }
                Afrag[gi][c] = a;
            }
        }
        #pragma unroll
        for (int c = 0; c < 4; ++c) {
            b1f[gi][c] = *(const f32x4*)(b1 + (size_t)d * U_ + c * 16 + q * 4);
            w2f[gi][c] = *(const f32x4*)(W2 + (size_t)d * U_ + c * 16 + q * 4);
        }
        b2s[gi] = b2[d];
    }

    // ---- per-thread staging constants ----
    // load i: flat = tid + i*256; row = (tid>>5) + 8i; (row&7) == (tid>>5)&7
    const int srow = tid >> 5;
    const int sb   = ((tid & 31) * 16) ^ ((srow & 7) << 4);
    const char* gx0 = (const char*)x
        + (size_t)(chunk * NT * BR) * (H_ * 4) + (size_t)d0 * V_ * 4;

    auto STAGE = [&](int buf, int t) {
        const char* s = gx0 + (size_t)t * (BR * H_ * 4)
                            + (size_t)srow * (H_ * 4) + sb;
        char* dl = (char*)&xs[buf][0] + tid * 16;
        #pragma unroll
        for (int i = 0; i < 8; ++i) {
            __builtin_amdgcn_global_load_lds((gptr_t)s, (sptr_t)dl, 16, 0, 0);
            s  += 8 * (H_ * 4);
            dl += 4096;
        }
    };

    STAGE(0, 0);
    __syncthreads();

    const int sw = (m & 7) << 4;          // read-side XOR (row&7 == m&7)

    for (int t = 0; t < NT; ++t) {
        const int buf = t & 1;
        if (t + 1 < NT) STAGE(buf ^ 1, t + 1);

        #pragma unroll
        for (int gi = 0; gi < 2; ++gi) {
            const int gl = wave * 2 + gi;
            #pragma unroll 2
            for (int tt = 0; tt < 4; ++tt) {
                const int row = tt * 16 + m;
                const char* xb = (const char*)&xs[buf][0] + row * 512;
                f32x4 x0 = *(const f32x4*)(xb + (((gl * V_ + vbase) * 4) ^ sw));
                f32x4 x1 = *(const f32x4*)(xb + (((gl * V_ + vbase + 4) * 4) ^ sw));
                float xf[8] = {x0.x, x0.y, x0.z, x0.w, x1.x, x1.y, x1.z, x1.w};
                bf16x8 bhi, blo;
                #pragma unroll
                for (int i = 0; i < 8; ++i) {
                    __bf16 h = (__bf16)xf[i];
                    bhi[i] = h;
                    blo[i] = (__bf16)(xf[i] - (float)h);
                }

                float partial = 0.0f;
                #pragma unroll
                for (int c = 0; c < 4; ++c) {
                    f32x4 acc = b1f[gi][c];
                    acc = __builtin_amdgcn_mfma_f32_16x16x32_bf16(Afrag[gi][c], bhi, acc, 0, 0, 0);
                    acc = __builtin_amdgcn_mfma_f32_16x16x32_bf16(Afrag[gi][c], blo, acc, 0, 0, 0);
                    #pragma unroll
                    for (int r = 0; r < 4; ++r) {
                        float h = acc[r];
                        // branchless ELU: max(h, expm1(min(h,0)))
                        float e = fmaxf(h, __expf(fminf(h, 0.0f)) - 1.0f);
                        partial = fmaf(w2f[gi][c][r], e, partial);
                    }
                }
                partial += __shfl_xor(partial, 16, 64);
                partial += __shfl_xor(partial, 32, 64);
                if (q == 0) {
                    yt[buf][row][gl] = partial + b2s[gi];
                }
            }
        }
        __syncthreads();

        // ---- coalesced y store for tile t (yt[buf] is free to re-read;
        // next overwrite of yt[buf] is after the NEXT barrier's lgkm drain) ----
        if (tid < 128) {
            const int row  = tid >> 1;
            const int half = tid & 1;
            f32x4 v = *(const f32x4*)&yt[buf][row][half * 4];
            const int r0 = (chunk * NT + t) * BR;
            *(f32x4*)(y + (size_t)(r0 + row) * D_ + d0 + half * 4) = v;
        }
    }
}

// Kernel 2: row-wise L2 normalize in place. One block (256 threads) per row.
__global__ __launch_bounds__(256) void k2_l2_normalize(float* __restrict__ y) {
    const int n = blockIdx.x;
    const int t = threadIdx.x;
    float* row = y + (size_t)n * D_;

    float v0 = row[t];
    float v1 = row[t + 256];
    float ss = v0 * v0 + v1 * v1;

    #pragma unroll
    for (int off = 32; off > 0; off >>= 1) {
        ss += __shfl_down(ss, off, 64);
    }

    __shared__ float wsum[4];
    if ((t & 63) == 0) wsum[t >> 6] = ss;
    __syncthreads();
    const float tot = wsum[0] + wsum[1] + wsum[2] + wsum[3];

    const float scale = 1.0f / fmaxf(sqrtf(tot), 1e-12f);

    row[t]       = v0 * scale;
    row[t + 256] = v1 * scale;
}

extern "C" void kernel_launch(void* const* d_in, const int* in_sizes, int n_in,
                              void* d_out, int out_size, void* d_ws, size_t ws_size,
                              hipStream_t stream) {
    const float* x  = (const float*)d_in[0];
    const float* W1 = (const float*)d_in[1];
    const float* b1 = (const float*)d_in[2];
    const float* W2 = (const float*)d_in[3];
    const float* b2 = (const float*)d_in[4];
    float* y = (float*)d_out;  // [N, D] fp32

    const dim3 grid((D_ / BG) * CH);   // 512 persistent blocks, all co-resident
    if (ws_size >= (size_t)(2 * DUV * sizeof(__bf16))) {
        __bf16* wh = (__bf16*)d_ws;
        k0_split_w1<<<dim3(DUV / 4 / 256), dim3(256), 0, stream>>>(W1, wh);
        k1_div_encoder<true><<<grid, dim3(256), 0, stream>>>(
            x, W1, wh, b1, W2, b2, y);
    } else {
        k1_div_encoder<false><<<grid, dim3(256), 0, stream>>>(
            x, W1, (const __bf16*)nullptr, b1, W2, b2, y);
    }
    k2_l2_normalize<<<dim3(N_), dim3(256), 0, stream>>>(y);
}

// Round 3
// 226.360 us; speedup vs baseline: 1.0048x; 1.0048x over previous
//
#include <hip/hip_runtime.h>
#include <math.h>

// DivEncoder: x[N,H] -> per-group (D=512 groups, V=16) conv to U=64, ELU,
// conv U->1, row-wise L2 normalize. All fp32 in/out.
#define D_ 512
#define H_ 8192
#define U_ 64
#define V_ 16
#define N_ 4096
#define DUV (D_ * U_ * V_)     // 524288

// k1 geometry: persistent blocks, 4 blocks/CU (occupancy was the round-2
// bottleneck: 70KB LDS -> 2 blocks/CU -> 17.6% occ, VALUBusy 45%).
// Tile = 32 rows x 8 groups, 256 threads (4 waves); each wave owns 2 groups,
// 2 row-subtiles. Double-buffered x staging via global_load_lds, STAGE(t+1)
// issued before compute(t), one barrier per tile. LDS = 35KB -> 4 blocks/CU.
#define BR 32
#define BG 8
#define NT 8                   // row-tiles per block
#define CH 16                  // chunks per group-slice (16*8*32 = 4096 rows)
#define YSTR 12                // 8 used + pad -> 16B-aligned f32x4 reads

typedef __bf16 bf16x8 __attribute__((ext_vector_type(8)));
typedef __bf16 bf16x4 __attribute__((ext_vector_type(4)));
typedef float f32x4 __attribute__((ext_vector_type(4)));

typedef const __attribute__((address_space(1))) char* gptr_t;
typedef __attribute__((address_space(3))) char* sptr_t;

// Prep: split W1 fp32 -> hi/lo bf16 (same [d][u][v] layout), once per launch.
__global__ __launch_bounds__(256) void k0_split_w1(const float* __restrict__ W1,
                                                   __bf16* __restrict__ wh) {
    __bf16* wl = wh + DUV;
    const int i4 = (blockIdx.x * 256 + threadIdx.x) * 4;
    f32x4 w = *(const f32x4*)(W1 + i4);
    bf16x4 h, l;
    #pragma unroll
    for (int j = 0; j < 4; ++j) {
        float wf = w[j];
        __bf16 hh = (__bf16)wf;
        h[j] = hh;
        l[j] = (__bf16)(wf - (float)hh);
    }
    *(bf16x4*)(wh + i4) = h;
    *(bf16x4*)(wl + i4) = l;
}

// Split-precision bf16 MFMA (16x16x32): K packs [w_hi | w_lo]:
//   MFMA1 B=[x_hi|x_hi] -> w*x_hi ; MFMA2 B=[x_lo|x_lo] -> w*x_lo
// Layouts (HW-verified): A/B: idx=lane&15, k=(lane>>4)*8+j ;
// C/D: col=lane&15, row=(lane>>4)*4+reg.
// LDS slot (row, s16) holds x[row][s16 ^ ((row&7)<<4)]: source-side swizzle
// keeps the LDS destination linear for global_load_lds; ds_read applies the
// same XOR (rule #21 both-sides). 16 m-lanes/quad -> 8 distinct 16B slots.
template <bool PRESPLIT>
__global__ __launch_bounds__(256, 4) void k1_div_encoder(
        const float* __restrict__ x,
        const float* __restrict__ W1,
        const __bf16* __restrict__ wsplit,
        const float* __restrict__ b1,
        const float* __restrict__ W2,
        const float* __restrict__ b2,
        float* __restrict__ y) {
    __shared__ float xs[2][BR * 128];     // 2 x 16 KB
    __shared__ float yt[2][BR][YSTR];     // 2 x 1.5 KB

    const int tid  = threadIdx.x;
    const int lane = tid & 63;
    const int wave = __builtin_amdgcn_readfirstlane(tid >> 6);
    const int q    = lane >> 4;
    const int m    = lane & 15;
    const int vbase = (q & 1) * 8;

    const int db    = blockIdx.x >> 4;   // 0..63 group-slice
    const int chunk = blockIdx.x & 15;   // 0..15 row-chunk (256 rows each)
    const int d0    = db * BG;

    // ---- load per-block weights once, held in registers for all tiles ----
    bf16x8 Afrag[2][4];
    f32x4  b1f[2][4], w2f[2][4];
    float  b2s[2];
    #pragma unroll
    for (int gi = 0; gi < 2; ++gi) {
        const int d = d0 + wave * 2 + gi;
        if (PRESPLIT) {
            const __bf16* base = wsplit + (size_t)(q >> 1) * DUV;
            #pragma unroll
            for (int c = 0; c < 4; ++c) {
                Afrag[gi][c] = *(const bf16x8*)(base +
                    ((size_t)d * U_ + c * 16 + m) * V_ + vbase);
            }
        } else {
            #pragma unroll
            for (int c = 0; c < 4; ++c) {
                const float* wp = W1 + ((size_t)d * U_ + c * 16 + m) * V_ + vbase;
                f32x4 w0 = *(const f32x4*)wp;
                f32x4 w1v = *(const f32x4*)(wp + 4);
                float wf[8] = {w0.x, w0.y, w0.z, w0.w, w1v.x, w1v.y, w1v.z, w1v.w};
                bf16x8 a;
                #pragma unroll
                for (int i = 0; i < 8; ++i) {
                    __bf16 h = (__bf16)wf[i];
                    __bf16 l = (__bf16)(wf[i] - (float)h);
                    a[i] = (q < 2) ? h : l;   // cndmask, branchless
                }
                Afrag[gi][c] = a;
            }
        }
        #pragma unroll
        for (int c = 0; c < 4; ++c) {
            b1f[gi][c] = *(const f32x4*)(b1 + (size_t)d * U_ + c * 16 + q * 4);
            w2f[gi][c] = *(const f32x4*)(W2 + (size_t)d * U_ + c * 16 + q * 4);
        }
        b2s[gi] = b2[d];
    }

    // ---- per-thread staging constants ----
    // load i: flat = tid + i*256; row = (tid>>5) + 8i; (row&7) == (tid>>5)&7
    const int srow = tid >> 5;                 // 0..7
    const int sb   = ((tid & 31) * 16) ^ ((srow & 7) << 4);
    const char* gx0 = (const char*)x
        + (size_t)(chunk * NT * BR) * (H_ * 4) + (size_t)d0 * V_ * 4;

    auto STAGE = [&](int buf, int t) {
        const char* s = gx0 + (size_t)t * (BR * H_ * 4)
                            + (size_t)srow * (H_ * 4) + sb;
        char* dl = (char*)&xs[buf][0] + tid * 16;
        #pragma unroll
        for (int i = 0; i < 4; ++i) {
            __builtin_amdgcn_global_load_lds((gptr_t)s, (sptr_t)dl, 16, 0, 0);
            s  += 8 * (H_ * 4);
            dl += 4096;
        }
    };

    STAGE(0, 0);
    __syncthreads();

    const int sw = (m & 7) << 4;          // read-side XOR (row&7 == m&7)

    for (int t = 0; t < NT; ++t) {
        const int buf = t & 1;
        if (t + 1 < NT) STAGE(buf ^ 1, t + 1);

        #pragma unroll
        for (int gi = 0; gi < 2; ++gi) {
            const int gl = wave * 2 + gi;
            #pragma unroll
            for (int tt = 0; tt < 2; ++tt) {
                const int row = tt * 16 + m;
                const char* xb = (const char*)&xs[buf][0] + row * 512;
                f32x4 x0 = *(const f32x4*)(xb + (((gl * V_ + vbase) * 4) ^ sw));
                f32x4 x1 = *(const f32x4*)(xb + (((gl * V_ + vbase + 4) * 4) ^ sw));
                float xf[8] = {x0.x, x0.y, x0.z, x0.w, x1.x, x1.y, x1.z, x1.w};
                bf16x8 bhi, blo;
                #pragma unroll
                for (int i = 0; i < 8; ++i) {
                    __bf16 h = (__bf16)xf[i];
                    bhi[i] = h;
                    blo[i] = (__bf16)(xf[i] - (float)h);
                }

                float partial = 0.0f;
                #pragma unroll
                for (int c = 0; c < 4; ++c) {
                    f32x4 acc = b1f[gi][c];
                    acc = __builtin_amdgcn_mfma_f32_16x16x32_bf16(Afrag[gi][c], bhi, acc, 0, 0, 0);
                    acc = __builtin_amdgcn_mfma_f32_16x16x32_bf16(Afrag[gi][c], blo, acc, 0, 0, 0);
                    #pragma unroll
                    for (int r = 0; r < 4; ++r) {
                        float h = acc[r];
                        // branchless ELU: max(h, expm1(min(h,0)))
                        float e = fmaxf(h, __expf(fminf(h, 0.0f)) - 1.0f);
                        partial = fmaf(w2f[gi][c][r], e, partial);
                    }
                }
                partial += __shfl_xor(partial, 16, 64);
                partial += __shfl_xor(partial, 32, 64);
                if (q == 0) {
                    yt[buf][row][gl] = partial + b2s[gi];
                }
            }
        }
        __syncthreads();

        // ---- coalesced y store for tile t (safe: yt[buf] is next written
        // in compute(t+2), which is separated by another barrier) ----
        if (tid < 64) {
            const int row  = tid >> 1;
            const int half = tid & 1;
            f32x4 v = *(const f32x4*)&yt[buf][row][half * 4];
            const int r0 = (chunk * NT + t) * BR;
            *(f32x4*)(y + (size_t)(r0 + row) * D_ + d0 + half * 4) = v;
        }
    }
}

// Kernel 2: row-wise L2 normalize in place. One block (256 threads) per row.
__global__ __launch_bounds__(256) void k2_l2_normalize(float* __restrict__ y) {
    const int n = blockIdx.x;
    const int t = threadIdx.x;
    float* row = y + (size_t)n * D_;

    float v0 = row[t];
    float v1 = row[t + 256];
    float ss = v0 * v0 + v1 * v1;

    #pragma unroll
    for (int off = 32; off > 0; off >>= 1) {
        ss += __shfl_down(ss, off, 64);
    }

    __shared__ float wsum[4];
    if ((t & 63) == 0) wsum[t >> 6] = ss;
    __syncthreads();
    const float tot = wsum[0] + wsum[1] + wsum[2] + wsum[3];

    const float scale = 1.0f / fmaxf(sqrtf(tot), 1e-12f);

    row[t]       = v0 * scale;
    row[t + 256] = v1 * scale;
}

extern "C" void kernel_launch(void* const* d_in, const int* in_sizes, int n_in,
                              void* d_out, int out_size, void* d_ws, size_t ws_size,
                              hipStream_t stream) {
    const float* x  = (const float*)d_in[0];
    const float* W1 = (const float*)d_in[1];
    const float* b1 = (const float*)d_in[2];
    const float* W2 = (const float*)d_in[3];
    const float* b2 = (const float*)d_in[4];
    float* y = (float*)d_out;  // [N, D] fp32

    const dim3 grid((D_ / BG) * CH);   // 1024 blocks = exactly 4/CU resident
    if (ws_size >= (size_t)(2 * DUV * sizeof(__bf16))) {
        __bf16* wh = (__bf16*)d_ws;
        k0_split_w1<<<dim3(DUV / 4 / 256), dim3(256), 0, stream>>>(W1, wh);
        k1_div_encoder<true><<<grid, dim3(256), 0, stream>>>(
            x, W1, wh, b1, W2, b2, y);
    } else {
        k1_div_encoder<false><<<grid, dim3(256), 0, stream>>>(
            x, W1, (const __bf16*)nullptr, b1, W2, b2, y);
    }
    k2_l2_normalize<<<dim3(N_), dim3(256), 0, stream>>>(y);
}

// Round 4
// 217.327 us; speedup vs baseline: 1.0466x; 1.0416x over previous
//
#include <hip/hip_runtime.h>
#include <math.h>

// DivEncoder: x[N,H] -> per-group (D=512 groups, V=16) conv to U=64, ELU,
// conv U->1, row-wise L2 normalize. All fp32 in/out.
#define D_ 512
#define H_ 8192
#define U_ 64
#define V_ 16
#define N_ 4096
#define DUV (D_ * U_ * V_)     // 524288

// k1 v4: barrier-free streaming. Rounds 2/3 showed the 2-phase LDS pipeline
// itself (stage -> vmcnt(0) -> barrier) was the critical path (m233: ~72%
// overhead; occupancy doubling was neutral). x has zero inter-block reuse,
// and the MFMA B-fragment is loadable directly from global as 2 aligned
// dwordx4/lane (wave covers 16 rows x 64B line-granular slices). So: no x
// LDS, no swizzle, no main-loop barriers. 512 blocks x 512 threads (8 waves,
// 1 group/wave -> weight regs ~halved), each wave streams NI=32 row-subtiles
// with 1-deep register prefetch; one barrier at the end for the coalescing
// y-transpose store.
#define BG 8                   // groups per block = waves per block
#define RB 512                 // rows per block
#define NI (RB / 16)           // 32 subtile iterations per wave
#define YSTR 12                // 8 used + pad

typedef __bf16 bf16x8 __attribute__((ext_vector_type(8)));
typedef __bf16 bf16x4 __attribute__((ext_vector_type(4)));
typedef float f32x4 __attribute__((ext_vector_type(4)));

// Prep: split W1 fp32 -> hi/lo bf16 (same [d][u][v] layout), once per launch.
__global__ __launch_bounds__(256) void k0_split_w1(const float* __restrict__ W1,
                                                   __bf16* __restrict__ wh) {
    __bf16* wl = wh + DUV;
    const int i4 = (blockIdx.x * 256 + threadIdx.x) * 4;
    f32x4 w = *(const f32x4*)(W1 + i4);
    bf16x4 h, l;
    #pragma unroll
    for (int j = 0; j < 4; ++j) {
        float wf = w[j];
        __bf16 hh = (__bf16)wf;
        h[j] = hh;
        l[j] = (__bf16)(wf - (float)hh);
    }
    *(bf16x4*)(wh + i4) = h;
    *(bf16x4*)(wl + i4) = l;
}

// Split-precision bf16 MFMA (16x16x32): A packs [w_hi | w_lo] along K:
//   MFMA1 B=[x_hi|x_hi] -> w*x_hi ; MFMA2 B=[x_lo|x_lo] -> w*x_lo
// Layouts (HW-verified): A/B: idx=lane&15, k=(lane>>4)*8+j ;
// C/D: col=lane&15, row=(lane>>4)*4+reg.
template <bool PRESPLIT>
__global__ __launch_bounds__(512, 4) void k1_div_encoder(
        const float* __restrict__ x,
        const float* __restrict__ W1,
        const __bf16* __restrict__ wsplit,
        const float* __restrict__ b1,
        const float* __restrict__ W2,
        const float* __restrict__ b2,
        float* __restrict__ y) {
    __shared__ float yt[RB][YSTR];        // 24 KB

    const int tid  = threadIdx.x;
    const int lane = tid & 63;
    const int wave = __builtin_amdgcn_readfirstlane(tid >> 6);  // 0..7
    const int q    = lane >> 4;
    const int m    = lane & 15;
    const int vbase = (q & 1) * 8;

    const int db = blockIdx.x & 63;       // 0..63 group-slice
    const int nb = blockIdx.x >> 6;       // 0..7 row-chunk (512 rows)
    const int d0 = db * BG;
    const int d  = d0 + wave;             // this wave's group
    const int r0 = nb * RB;

    // ---- per-wave weights, loaded once, resident for all 32 iterations ----
    bf16x8 Af[4];
    f32x4  b1f[4], w2f[4];
    if (PRESPLIT) {
        const __bf16* base = wsplit + (size_t)(q >> 1) * DUV;
        #pragma unroll
        for (int c = 0; c < 4; ++c) {
            Af[c] = *(const bf16x8*)(base +
                ((size_t)d * U_ + c * 16 + m) * V_ + vbase);
        }
    } else {
        #pragma unroll
        for (int c = 0; c < 4; ++c) {
            const float* wp = W1 + ((size_t)d * U_ + c * 16 + m) * V_ + vbase;
            f32x4 w0 = *(const f32x4*)wp;
            f32x4 w1v = *(const f32x4*)(wp + 4);
            float wf[8] = {w0.x, w0.y, w0.z, w0.w, w1v.x, w1v.y, w1v.z, w1v.w};
            bf16x8 a;
            #pragma unroll
            for (int i = 0; i < 8; ++i) {
                __bf16 h = (__bf16)wf[i];
                __bf16 l = (__bf16)(wf[i] - (float)h);
                a[i] = (q < 2) ? h : l;   // cndmask, branchless
            }
            Af[c] = a;
        }
    }
    #pragma unroll
    for (int c = 0; c < 4; ++c) {
        b1f[c] = *(const f32x4*)(b1 + (size_t)d * U_ + c * 16 + q * 4);
        w2f[c] = *(const f32x4*)(W2 + (size_t)d * U_ + c * 16 + q * 4);
    }
    const float b2s = b2[d];

    // ---- streaming main loop: direct global loads of the B-fragment ----
    // lane (q,m) iter it: x[r0 + it*16 + m][d*16 + vbase .. +8] (32B, aligned)
    const float* lp = x + (size_t)(r0 + m) * H_ + d * V_ + vbase;

    f32x4 c0 = *(const f32x4*)lp;
    f32x4 c1 = *(const f32x4*)(lp + 4);
    lp += (size_t)16 * H_;

    #pragma unroll 2
    for (int it = 0; it < NI; ++it) {
        f32x4 n0 = {}, n1 = {};
        if (it + 1 < NI) {
            n0 = *(const f32x4*)lp;
            n1 = *(const f32x4*)(lp + 4);
            lp += (size_t)16 * H_;
        }

        float xf[8] = {c0.x, c0.y, c0.z, c0.w, c1.x, c1.y, c1.z, c1.w};
        bf16x8 bhi, blo;
        #pragma unroll
        for (int i = 0; i < 8; ++i) {
            __bf16 h = (__bf16)xf[i];
            bhi[i] = h;
            blo[i] = (__bf16)(xf[i] - (float)h);
        }

        float partial = 0.0f;
        #pragma unroll
        for (int c = 0; c < 4; ++c) {
            f32x4 acc = b1f[c];
            acc = __builtin_amdgcn_mfma_f32_16x16x32_bf16(Af[c], bhi, acc, 0, 0, 0);
            acc = __builtin_amdgcn_mfma_f32_16x16x32_bf16(Af[c], blo, acc, 0, 0, 0);
            #pragma unroll
            for (int r = 0; r < 4; ++r) {
                float h = acc[r];
                // branchless ELU: max(h, expm1(min(h,0)))
                float e = fmaxf(h, __expf(fminf(h, 0.0f)) - 1.0f);
                partial = fmaf(w2f[c][r], e, partial);
            }
        }
        partial += __shfl_xor(partial, 16, 64);
        partial += __shfl_xor(partial, 32, 64);
        if (q == 0) {
            yt[it * 16 + m][wave] = partial + b2s;
        }
        c0 = n0;
        c1 = n1;
    }
    __syncthreads();

    // ---- coalescing y store: thread tid handles row tid (32B contiguous) ----
    {
        f32x4 v0 = *(const f32x4*)&yt[tid][0];
        f32x4 v1 = *(const f32x4*)&yt[tid][4];
        float* yp = y + (size_t)(r0 + tid) * D_ + d0;
        *(f32x4*)yp = v0;
        *(f32x4*)(yp + 4) = v1;
    }
}

// Kernel 2: row-wise L2 normalize in place. One block (256 threads) per row.
__global__ __launch_bounds__(256) void k2_l2_normalize(float* __restrict__ y) {
    const int n = blockIdx.x;
    const int t = threadIdx.x;
    float* row = y + (size_t)n * D_;

    float v0 = row[t];
    float v1 = row[t + 256];
    float ss = v0 * v0 + v1 * v1;

    #pragma unroll
    for (int off = 32; off > 0; off >>= 1) {
        ss += __shfl_down(ss, off, 64);
    }

    __shared__ float wsum[4];
    if ((t & 63) == 0) wsum[t >> 6] = ss;
    __syncthreads();
    const float tot = wsum[0] + wsum[1] + wsum[2] + wsum[3];

    const float scale = 1.0f / fmaxf(sqrtf(tot), 1e-12f);

    row[t]       = v0 * scale;
    row[t + 256] = v1 * scale;
}

extern "C" void kernel_launch(void* const* d_in, const int* in_sizes, int n_in,
                              void* d_out, int out_size, void* d_ws, size_t ws_size,
                              hipStream_t stream) {
    const float* x  = (const float*)d_in[0];
    const float* W1 = (const float*)d_in[1];
    const float* b1 = (const float*)d_in[2];
    const float* W2 = (const float*)d_in[3];
    const float* b2 = (const float*)d_in[4];
    float* y = (float*)d_out;  // [N, D] fp32

    const dim3 grid((N_ / RB) * (D_ / BG));   // 512 blocks, all co-resident
    if (ws_size >= (size_t)(2 * DUV * sizeof(__bf16))) {
        __bf16* wh = (__bf16*)d_ws;
        k0_split_w1<<<dim3(DUV / 4 / 256), dim3(256), 0, stream>>>(W1, wh);
        k1_div_encoder<true><<<grid, dim3(512), 0, stream>>>(
            x, W1, wh, b1, W2, b2, y);
    } else {
        k1_div_encoder<false><<<grid, dim3(512), 0, stream>>>(
            x, W1, (const __bf16*)nullptr, b1, W2, b2, y);
    }
    k2_l2_normalize<<<dim3(N_), dim3(256), 0, stream>>>(y);
}

// Round 5
// 215.707 us; speedup vs baseline: 1.0545x; 1.0075x over previous
//
#include <hip/hip_runtime.h>
#include <math.h>

// DivEncoder: x[N,H] -> per-group (D=512 groups, V=16) conv to U=64, ELU,
// conv U->1, row-wise L2 normalize. All fp32 in/out.
#define D_ 512
#define H_ 8192
#define U_ 64
#define V_ 16
#define N_ 4096
#define DUV (D_ * U_ * V_)     // 524288

// k1 v5: barrier-free streaming (v4) + 2 independent subtile chains per
// iteration. v4 showed one serial chain/wave leaves the SIMD idle (load-wait
// -> split -> MFMA dep -> ELU -> serial fma -> 2 serial shuffles); pairing
// two 16-row subtiles lets the scheduler cover every latency of chain A with
// issue of chain B, and doubles the absolute prefetch distance. 512 blocks x
// 512 threads (8 waves, 1 group/wave), NI=16 iters x 32 rows, no main-loop
// barriers; one barrier before the coalescing y-transpose store.
#define BG 8                   // groups per block = waves per block
#define RB 512                 // rows per block
#define NI 16                  // iterations (32 rows each)
#define YSTR 12                // 8 used + pad

typedef __bf16 bf16x8 __attribute__((ext_vector_type(8)));
typedef __bf16 bf16x4 __attribute__((ext_vector_type(4)));
typedef float f32x4 __attribute__((ext_vector_type(4)));

// Prep: split W1 fp32 -> hi/lo bf16 (same [d][u][v] layout), once per launch.
__global__ __launch_bounds__(256) void k0_split_w1(const float* __restrict__ W1,
                                                   __bf16* __restrict__ wh) {
    __bf16* wl = wh + DUV;
    const int i4 = (blockIdx.x * 256 + threadIdx.x) * 4;
    f32x4 w = *(const f32x4*)(W1 + i4);
    bf16x4 h, l;
    #pragma unroll
    for (int j = 0; j < 4; ++j) {
        float wf = w[j];
        __bf16 hh = (__bf16)wf;
        h[j] = hh;
        l[j] = (__bf16)(wf - (float)hh);
    }
    *(bf16x4*)(wh + i4) = h;
    *(bf16x4*)(wl + i4) = l;
}

// Split-precision bf16 MFMA (16x16x32): A packs [w_hi | w_lo] along K:
//   MFMA1 B=[x_hi|x_hi], MFMA2 B=[x_lo|x_lo]; sum = (whi+wlo)(xhi+xlo) ~ w*x.
// Layouts (HW-verified): A/B: idx=lane&15, k=(lane>>4)*8+j ;
// C/D: col=lane&15, row=(lane>>4)*4+reg.
template <bool PRESPLIT>
__global__ __launch_bounds__(512, 4) void k1_div_encoder(
        const float* __restrict__ x,
        const float* __restrict__ W1,
        const __bf16* __restrict__ wsplit,
        const float* __restrict__ b1,
        const float* __restrict__ W2,
        const float* __restrict__ b2,
        float* __restrict__ y) {
    __shared__ float yt[RB][YSTR];        // 24 KB

    const int tid  = threadIdx.x;
    const int lane = tid & 63;
    const int wave = __builtin_amdgcn_readfirstlane(tid >> 6);  // 0..7
    const int q    = lane >> 4;
    const int m    = lane & 15;
    const int vbase = (q & 1) * 8;

    const int db = blockIdx.x & 63;       // 0..63 group-slice
    const int nb = blockIdx.x >> 6;       // 0..7 row-chunk (512 rows)
    const int d0 = db * BG;
    const int d  = d0 + wave;             // this wave's group
    const int r0 = nb * RB;

    // ---- per-wave weights, loaded once, resident for all iterations ----
    bf16x8 Af[4];
    f32x4  b1f[4], w2f[4];
    if (PRESPLIT) {
        const __bf16* base = wsplit + (size_t)(q >> 1) * DUV;
        #pragma unroll
        for (int c = 0; c < 4; ++c) {
            Af[c] = *(const bf16x8*)(base +
                ((size_t)d * U_ + c * 16 + m) * V_ + vbase);
        }
    } else {
        #pragma unroll
        for (int c = 0; c < 4; ++c) {
            const float* wp = W1 + ((size_t)d * U_ + c * 16 + m) * V_ + vbase;
            f32x4 w0 = *(const f32x4*)wp;
            f32x4 w1v = *(const f32x4*)(wp + 4);
            float wf[8] = {w0.x, w0.y, w0.z, w0.w, w1v.x, w1v.y, w1v.z, w1v.w};
            bf16x8 a;
            #pragma unroll
            for (int i = 0; i < 8; ++i) {
                __bf16 h = (__bf16)wf[i];
                __bf16 l = (__bf16)(wf[i] - (float)h);
                a[i] = (q < 2) ? h : l;   // cndmask, branchless
            }
            Af[c] = a;
        }
    }
    #pragma unroll
    for (int c = 0; c < 4; ++c) {
        b1f[c] = *(const f32x4*)(b1 + (size_t)d * U_ + c * 16 + q * 4);
        w2f[c] = *(const f32x4*)(W2 + (size_t)d * U_ + c * 16 + q * 4);
    }
    const float b2s = b2[d];

    // one 16-row subtile -> this lane's partial of the U-reduction
    auto compute16 = [&](f32x4 x0, f32x4 x1) -> float {
        float xf[8] = {x0.x, x0.y, x0.z, x0.w, x1.x, x1.y, x1.z, x1.w};
        bf16x8 bhi, blo;
        #pragma unroll
        for (int i = 0; i < 8; ++i) {
            __bf16 h = (__bf16)xf[i];
            bhi[i] = h;
            blo[i] = (__bf16)(xf[i] - (float)h);
        }
        float partial = 0.0f;
        #pragma unroll
        for (int c = 0; c < 4; ++c) {
            f32x4 acc = b1f[c];
            acc = __builtin_amdgcn_mfma_f32_16x16x32_bf16(Af[c], bhi, acc, 0, 0, 0);
            acc = __builtin_amdgcn_mfma_f32_16x16x32_bf16(Af[c], blo, acc, 0, 0, 0);
            #pragma unroll
            for (int r = 0; r < 4; ++r) {
                float h = acc[r];
                // branchless ELU: max(h, expm1(min(h,0)))
                float e = fmaxf(h, __expf(fminf(h, 0.0f)) - 1.0f);
                partial = fmaf(w2f[c][r], e, partial);
            }
        }
        return partial;
    };

    // ---- streaming main loop: 2 independent subtiles (rows +0, +16) ----
    // lane (q,m): x[r0 + it*32 + {m, 16+m}][d*16 + vbase .. +8] (32B aligned)
    const float* baseA = x + (size_t)(r0 + m) * H_ + d * V_ + vbase;
    const float* baseB = baseA + (size_t)16 * H_;
    const size_t stride = (size_t)32 * H_;

    f32x4 a0 = *(const f32x4*)baseA;
    f32x4 a1 = *(const f32x4*)(baseA + 4);
    f32x4 b0 = *(const f32x4*)baseB;
    f32x4 b1v = *(const f32x4*)(baseB + 4);

    for (int it = 0; it < NI; ++it) {
        // prefetch next iteration (uniform SGPR offset, clamped in-bounds)
        const size_t offn = (size_t)(it + 1 < NI ? it + 1 : it) * stride;
        f32x4 na0 = *(const f32x4*)(baseA + offn);
        f32x4 na1 = *(const f32x4*)(baseA + offn + 4);
        f32x4 nb0 = *(const f32x4*)(baseB + offn);
        f32x4 nb1 = *(const f32x4*)(baseB + offn + 4);

        float pA = compute16(a0, a1);
        float pB = compute16(b0, b1v);

        pA += __shfl_xor(pA, 16, 64);
        pB += __shfl_xor(pB, 16, 64);
        pA += __shfl_xor(pA, 32, 64);
        pB += __shfl_xor(pB, 32, 64);
        if (q == 0) {
            yt[it * 32 + m][wave]      = pA + b2s;
            yt[it * 32 + 16 + m][wave] = pB + b2s;
        }
        a0 = na0; a1 = na1; b0 = nb0; b1v = nb1;
    }
    __syncthreads();

    // ---- coalescing y store: thread tid handles row tid (32B contiguous) ----
    {
        f32x4 v0 = *(const f32x4*)&yt[tid][0];
        f32x4 v1 = *(const f32x4*)&yt[tid][4];
        float* yp = y + (size_t)(r0 + tid) * D_ + d0;
        *(f32x4*)yp = v0;
        *(f32x4*)(yp + 4) = v1;
    }
}

// Kernel 2: row-wise L2 normalize in place. One block (256 threads) per row.
__global__ __launch_bounds__(256) void k2_l2_normalize(float* __restrict__ y) {
    const int n = blockIdx.x;
    const int t = threadIdx.x;
    float* row = y + (size_t)n * D_;

    float v0 = row[t];
    float v1 = row[t + 256];
    float ss = v0 * v0 + v1 * v1;

    #pragma unroll
    for (int off = 32; off > 0; off >>= 1) {
        ss += __shfl_down(ss, off, 64);
    }

    __shared__ float wsum[4];
    if ((t & 63) == 0) wsum[t >> 6] = ss;
    __syncthreads();
    const float tot = wsum[0] + wsum[1] + wsum[2] + wsum[3];

    const float scale = 1.0f / fmaxf(sqrtf(tot), 1e-12f);

    row[t]       = v0 * scale;
    row[t + 256] = v1 * scale;
}

extern "C" void kernel_launch(void* const* d_in, const int* in_sizes, int n_in,
                              void* d_out, int out_size, void* d_ws, size_t ws_size,
                              hipStream_t stream) {
    const float* x  = (const float*)d_in[0];
    const float* W1 = (const float*)d_in[1];
    const float* b1 = (const float*)d_in[2];
    const float* W2 = (const float*)d_in[3];
    const float* b2 = (const float*)d_in[4];
    float* y = (float*)d_out;  // [N, D] fp32

    const dim3 grid((N_ / RB) * (D_ / BG));   // 512 blocks, all co-resident
    if (ws_size >= (size_t)(2 * DUV * sizeof(__bf16))) {
        __bf16* wh = (__bf16*)d_ws;
        k0_split_w1<<<dim3(DUV / 4 / 256), dim3(256), 0, stream>>>(W1, wh);
        k1_div_encoder<true><<<grid, dim3(512), 0, stream>>>(
            x, W1, wh, b1, W2, b2, y);
    } else {
        k1_div_encoder<false><<<grid, dim3(512), 0, stream>>>(
            x, W1, (const __bf16*)nullptr, b1, W2, b2, y);
    }
    k2_l2_normalize<<<dim3(N_), dim3(256), 0, stream>>>(y);
}